// Round 1
// baseline (308.725 us; speedup 1.0000x reference)
//
#include <hip/hip_runtime.h>
#include <hip/hip_bf16.h>

// Spatial Transformer Layer, fp32 end-to-end.
// Stages:
//  k_conv1: conv7x7(3->8)+bias+relu+BN+maxpool2 -> p1 [64,109,109,8]
//  k_conv2: conv5x5(8->10)+bias+relu+BN+maxpool2 -> p2 [64,52,52,10]
//  k_fc1:   split-K partial GEMM [64,27040]x[27040,32] -> partial[212][64*32]
//  k_fc2:   reduce + bias + relu + dense2(32->6) + bias -> theta [64,6]
//  k_sample: affine grid + bilinear sampling -> out [64,224,224,3]

#define BB 64
#define HH 224
#define WW 224
#define CC 3

// ---------------- conv1: 7x7, 3->8, then relu, BN, maxpool2 ----------------
// pooled output 109x109x8. Tile 16x16 pooled pixels per block (256 threads).
// Input tile needed: 38x38x3 floats.
__global__ __launch_bounds__(256) void k_conv1(
    const float* __restrict__ x, const float* __restrict__ w,
    const float* __restrict__ bias, const float* __restrict__ g,
    const float* __restrict__ bt, const float* __restrict__ m,
    const float* __restrict__ v, float* __restrict__ out) {
  __shared__ float s_in[38 * 114];   // [row][col*3+ci], row stride 114
  __shared__ float s_w[7 * 7 * 3 * 8];
  __shared__ float s_scale[8], s_shift[8], s_bias[8];
  const int tid = threadIdx.x;
  const int bx = blockIdx.x, by = blockIdx.y, b = blockIdx.z;

  for (int f = tid; f < 1176; f += 256) s_w[f] = w[f];
  if (tid < 8) {
    float sc = g[tid] * rsqrtf(v[tid] + 1e-3f);
    s_scale[tid] = sc;
    s_shift[tid] = bt[tid] - m[tid] * sc;
    s_bias[tid] = bias[tid];
  }
  const int iy0 = by * 32, ix0 = bx * 32;
  const float* xb = x + (size_t)b * HH * WW * CC;
  for (int f = tid; f < 38 * 114; f += 256) {
    int r = f / 114, rem = f - r * 114;
    int q = rem / 3, c = rem - q * 3;
    int gy = iy0 + r; if (gy > 223) gy = 223;
    int gc = ix0 + q; if (gc > 223) gc = 223;
    s_in[f] = xb[(gy * 224 + gc) * 3 + c];
  }
  __syncthreads();

  const int pyl = tid >> 4, pxl = tid & 15;
  const int ly = 2 * pyl, lx = 2 * pxl;
  float acc[4][8];
#pragma unroll
  for (int i = 0; i < 4; i++)
#pragma unroll
    for (int j = 0; j < 8; j++) acc[i][j] = 0.f;

#pragma unroll 1
  for (int ky = 0; ky < 7; ky++) {
#pragma unroll
    for (int kx = 0; kx < 7; kx++) {
#pragma unroll
      for (int ci = 0; ci < 3; ci++) {
        const int r0 = (ly + ky) * 114 + (lx + kx) * 3 + ci;
        const int r1 = r0 + 114;
        float i00 = s_in[r0], i01 = s_in[r0 + 3];
        float i10 = s_in[r1], i11 = s_in[r1 + 3];
        const float* wp = &s_w[((ky * 7 + kx) * 3 + ci) * 8];
#pragma unroll
        for (int co = 0; co < 8; co++) {
          float wv = wp[co];
          acc[0][co] = fmaf(i00, wv, acc[0][co]);
          acc[1][co] = fmaf(i01, wv, acc[1][co]);
          acc[2][co] = fmaf(i10, wv, acc[2][co]);
          acc[3][co] = fmaf(i11, wv, acc[3][co]);
        }
      }
    }
  }

  const int py = by * 16 + pyl, px = bx * 16 + pxl;
  if (py < 109 && px < 109) {
    float res[8];
#pragma unroll
    for (int co = 0; co < 8; co++) {
      float sc = s_scale[co], sh = s_shift[co], bs = s_bias[co];
      float a0 = fmaxf(acc[0][co] + bs, 0.f) * sc + sh;
      float a1 = fmaxf(acc[1][co] + bs, 0.f) * sc + sh;
      float a2 = fmaxf(acc[2][co] + bs, 0.f) * sc + sh;
      float a3 = fmaxf(acc[3][co] + bs, 0.f) * sc + sh;
      res[co] = fmaxf(fmaxf(a0, a1), fmaxf(a2, a3));
    }
    float4* op = (float4*)&out[(((size_t)b * 109 + py) * 109 + px) * 8];
    op[0] = make_float4(res[0], res[1], res[2], res[3]);
    op[1] = make_float4(res[4], res[5], res[6], res[7]);
  }
}

// ---------------- conv2: 5x5, 8->10, then relu, BN, maxpool2 ----------------
// input p1 [64,109,109,8], pooled output 52x52x10. Tile 16x16 pooled pixels.
// Input tile: 36x36x8 floats.
__global__ __launch_bounds__(256) void k_conv2(
    const float* __restrict__ in, const float* __restrict__ w,
    const float* __restrict__ bias, const float* __restrict__ g,
    const float* __restrict__ bt, const float* __restrict__ m,
    const float* __restrict__ v, float* __restrict__ out) {
  __shared__ float s_in[36 * 288];   // [row][col*8+ci], row stride 288
  __shared__ float s_w[5 * 5 * 8 * 10];
  __shared__ float s_scale[10], s_shift[10], s_bias[10];
  const int tid = threadIdx.x;
  const int bx = blockIdx.x, by = blockIdx.y, b = blockIdx.z;

  for (int f = tid; f < 2000; f += 256) s_w[f] = w[f];
  if (tid < 10) {
    float sc = g[tid] * rsqrtf(v[tid] + 1e-3f);
    s_scale[tid] = sc;
    s_shift[tid] = bt[tid] - m[tid] * sc;
    s_bias[tid] = bias[tid];
  }
  const int iy0 = by * 32, ix0 = bx * 32;
  const float* ib = in + (size_t)b * 109 * 109 * 8;
  for (int f = tid; f < 36 * 288; f += 256) {
    int r = f / 288, rem = f - r * 288;
    int q = rem >> 3, c = rem & 7;
    int gy = iy0 + r; if (gy > 108) gy = 108;
    int gc = ix0 + q; if (gc > 108) gc = 108;
    s_in[f] = ib[(gy * 109 + gc) * 8 + c];
  }
  __syncthreads();

  const int pyl = tid >> 4, pxl = tid & 15;
  const int ly = 2 * pyl, lx = 2 * pxl;
  float acc[4][10];
#pragma unroll
  for (int i = 0; i < 4; i++)
#pragma unroll
    for (int j = 0; j < 10; j++) acc[i][j] = 0.f;

#pragma unroll 1
  for (int ky = 0; ky < 5; ky++) {
#pragma unroll
    for (int kx = 0; kx < 5; kx++) {
#pragma unroll
      for (int ci = 0; ci < 8; ci++) {
        const int r0 = (ly + ky) * 288 + (lx + kx) * 8 + ci;
        const int r1 = r0 + 288;
        float i00 = s_in[r0], i01 = s_in[r0 + 8];
        float i10 = s_in[r1], i11 = s_in[r1 + 8];
        const float* wp = &s_w[((ky * 5 + kx) * 8 + ci) * 10];
#pragma unroll
        for (int co = 0; co < 10; co++) {
          float wv = wp[co];
          acc[0][co] = fmaf(i00, wv, acc[0][co]);
          acc[1][co] = fmaf(i01, wv, acc[1][co]);
          acc[2][co] = fmaf(i10, wv, acc[2][co]);
          acc[3][co] = fmaf(i11, wv, acc[3][co]);
        }
      }
    }
  }

  const int py = by * 16 + pyl, px = bx * 16 + pxl;
  if (py < 52 && px < 52) {
    float res[10];
#pragma unroll
    for (int co = 0; co < 10; co++) {
      float sc = s_scale[co], sh = s_shift[co], bs = s_bias[co];
      float a0 = fmaxf(acc[0][co] + bs, 0.f) * sc + sh;
      float a1 = fmaxf(acc[1][co] + bs, 0.f) * sc + sh;
      float a2 = fmaxf(acc[2][co] + bs, 0.f) * sc + sh;
      float a3 = fmaxf(acc[3][co] + bs, 0.f) * sc + sh;
      res[co] = fmaxf(fmaxf(a0, a1), fmaxf(a2, a3));
    }
    float* op = &out[(((size_t)b * 52 + py) * 52 + px) * 10];
    float2* op2 = (float2*)op;
#pragma unroll
    for (int i = 0; i < 5; i++)
      op2[i] = make_float2(res[2 * i], res[2 * i + 1]);
  }
}

// ---------------- fc1 split-K: [64,27040] x [27040,32] ----------------
// 212 chunks of K=128. Each block stages s_a[64][128] + s_w[128][32] and
// writes a full [64,32] partial.
#define NCHUNK 212
#define KC 128
__global__ __launch_bounds__(256) void k_fc1(
    const float* __restrict__ act, const float* __restrict__ w,
    float* __restrict__ partial) {
  __shared__ float s_w[KC * 32];    // 16 KB
  __shared__ float s_a[64 * KC];    // 32 KB
  const int tid = threadIdx.x;
  const int chunk = blockIdx.x;
  const int k0 = chunk * KC;
  for (int f = tid; f < KC * 32; f += 256) {
    int k = k0 + (f >> 5);
    s_w[f] = (k < 27040) ? w[(size_t)k0 * 32 + f] : 0.f;
  }
  for (int f = tid; f < 64 * KC; f += 256) {
    int bb = f >> 7, j = f & (KC - 1);
    int k = k0 + j;
    s_a[f] = (k < 27040) ? act[(size_t)bb * 27040 + k] : 0.f;
  }
  __syncthreads();
  const int o = tid & 31, bh = tid >> 5;
  float sums[8];
#pragma unroll
  for (int i = 0; i < 8; i++) sums[i] = 0.f;
#pragma unroll 1
  for (int j = 0; j < KC; j++) {
    float wv = s_w[j * 32 + o];
#pragma unroll
    for (int i = 0; i < 8; i++)
      sums[i] = fmaf(s_a[(i * 8 + bh) * KC + j], wv, sums[i]);
  }
#pragma unroll
  for (int i = 0; i < 8; i++)
    partial[(size_t)chunk * 2048 + i * 256 + tid] = sums[i];
}

// ---------------- fc2: reduce partials, relu, dense2 -> theta [64,6] -------
__global__ __launch_bounds__(64) void k_fc2(
    const float* __restrict__ partial, const float* __restrict__ d1b,
    const float* __restrict__ d2w, const float* __restrict__ d2b,
    float* __restrict__ theta) {
  const int b = blockIdx.x;
  const int t = threadIdx.x;
  const int o = t & 31, half = t >> 5;
  float s = 0.f;
  const int c0 = half * (NCHUNK / 2), c1 = c0 + (NCHUNK / 2);
  for (int c = c0; c < c1; c++)
    s += partial[(size_t)c * 2048 + b * 32 + o];
  s += __shfl_down(s, 32);
  __shared__ float s_h[32];
  if (t < 32) s_h[o] = fmaxf(s + d1b[o], 0.f);
  __syncthreads();
  if (t < 6) {
    float th = d2b[t];
#pragma unroll
    for (int o2 = 0; o2 < 32; o2++) th = fmaf(s_h[o2], d2w[o2 * 6 + t], th);
    theta[b * 6 + t] = th;
  }
}

// ---------------- sampler: affine grid + bilinear, zero outside ------------
__global__ __launch_bounds__(256) void k_sample(
    const float* __restrict__ x, const float* __restrict__ theta,
    float* __restrict__ out) {
  const int b = blockIdx.y;
  __shared__ float th[6];
  if (threadIdx.x < 6) th[threadIdx.x] = theta[b * 6 + threadIdx.x];
  __syncthreads();
  const int t = blockIdx.x * 256 + threadIdx.x;  // grid sized exactly 50176
  const int oy = t / 224, ox = t - oy * 224;
  const float xn = -1.f + (2.f / 223.f) * (float)ox;
  const float yn = -1.f + (2.f / 223.f) * (float)oy;
  const float cx = th[0] * xn + th[1] * yn + th[2];
  const float cy = th[3] * xn + th[4] * yn + th[5];
  const float px = (cx + 1.f) * 0.5f * 223.f;
  const float py = (cy + 1.f) * 0.5f * 223.f;
  const float x0f = floorf(px), y0f = floorf(py);
  const int x0 = (int)x0f, y0 = (int)y0f;
  const float wx = px - x0f, wy = py - y0f;
  const float* xb = x + (size_t)b * HH * WW * CC;
  float a0 = 0.f, a1 = 0.f, a2 = 0.f;
#pragma unroll
  for (int dy = 0; dy < 2; dy++) {
    const int yi = y0 + dy;
    const bool vy = (yi >= 0) && (yi < 224);
    const int yc = yi < 0 ? 0 : (yi > 223 ? 223 : yi);
    const float wyv = dy ? wy : 1.f - wy;
#pragma unroll
    for (int dx = 0; dx < 2; dx++) {
      const int xi = x0 + dx;
      const bool vx = (xi >= 0) && (xi < 224);
      const int xc = xi < 0 ? 0 : (xi > 223 ? 223 : xi);
      const float wv = wyv * (dx ? wx : 1.f - wx) * ((vx && vy) ? 1.f : 0.f);
      const float* p = &xb[(yc * 224 + xc) * 3];
      a0 = fmaf(p[0], wv, a0);
      a1 = fmaf(p[1], wv, a1);
      a2 = fmaf(p[2], wv, a2);
    }
  }
  float* op = &out[((size_t)b * 50176 + t) * 3];
  op[0] = a0; op[1] = a1; op[2] = a2;
}

extern "C" void kernel_launch(void* const* d_in, const int* in_sizes, int n_in,
                              void* d_out, int out_size, void* d_ws, size_t ws_size,
                              hipStream_t stream) {
  const float* x    = (const float*)d_in[0];
  const float* c1w  = (const float*)d_in[1];
  const float* c1b  = (const float*)d_in[2];
  const float* g1   = (const float*)d_in[3];
  const float* b1   = (const float*)d_in[4];
  const float* m1   = (const float*)d_in[5];
  const float* v1   = (const float*)d_in[6];
  const float* c2w  = (const float*)d_in[7];
  const float* c2b  = (const float*)d_in[8];
  const float* g2   = (const float*)d_in[9];
  const float* b2   = (const float*)d_in[10];
  const float* m2   = (const float*)d_in[11];
  const float* v2   = (const float*)d_in[12];
  const float* d1w  = (const float*)d_in[13];
  const float* d1b  = (const float*)d_in[14];
  const float* d2w  = (const float*)d_in[15];
  const float* d2b  = (const float*)d_in[16];
  float* out = (float*)d_out;

  float* ws = (float*)d_ws;
  float* p1    = ws;                    // 64*109*109*8 = 6,083,072 floats
  float* p2    = p1 + 6083072;          // 64*52*52*10  = 1,730,560 floats
  float* part  = p2 + 1730560;          // 212*2048     =   434,176 floats
  float* theta = part + (size_t)NCHUNK * 2048;  // 384 floats

  k_conv1<<<dim3(7, 7, 64), 256, 0, stream>>>(x, c1w, c1b, g1, b1, m1, v1, p1);
  k_conv2<<<dim3(4, 4, 64), 256, 0, stream>>>(p1, c2w, c2b, g2, b2, m2, v2, p2);
  k_fc1<<<NCHUNK, 256, 0, stream>>>(p2, d1w, part);
  k_fc2<<<64, 64, 0, stream>>>(part, d1b, d2w, d2b, theta);
  k_sample<<<dim3(196, 64), 256, 0, stream>>>(x, theta, out);
}